// Round 7
// baseline (839.231 us; speedup 1.0000x reference)
//
#include <hip/hip_runtime.h>
#include <hip/hip_bf16.h>

// TensorTrainLMN: out[b, a*128+h] = X[b,:] @ W[:, a*128+h] + bias
//   X[b] = [nh[b,0,:128], ..., nh[b,15,:128], te[b,:128]]   (K = 2176)
// tt_fold: folds A@B^(15-c)@U_out (exact f32) into W bf16, PRE-PACKED in MFMA
//   B-fragment order: Wp[kt][slot=k8][n 0..511][8 bf16]. 512 threads/block
//   (halves the serial matmul critical path vs 256).
// tt_gemm: A-only-LDS MFMA GEMM (W 2.2MB = L2-resident, B-frags global->VGPR).
//   256 thr / 4 waves, block 64Mx256N, wave 64x64, BK=64. Fully pipelined:
//   B-frags distance-1 named double-buffer (bFA/bFB), A distance-2 (va0/va1),
//   so no load latency is exposed inside an iteration. 4 waves/SIMD kept
//   (arch-VGPR ~120 <= 128; acc in AGPRs).

typedef short bf16x8 __attribute__((ext_vector_type(8)));
typedef float f32x4  __attribute__((ext_vector_type(4)));

__device__ __forceinline__ unsigned f2bfbits(float f) {
    unsigned u = __builtin_bit_cast(unsigned, f);
    return (u + 0x7FFFu + ((u >> 16) & 1u)) >> 16;   // round-to-nearest-even
}
// compiler fuses pairs of scalar casts into v_cvt_pk_bf16_f32 (m240)
__device__ __forceinline__ unsigned pack2(float a, float b) {
    unsigned lo = (unsigned)__builtin_bit_cast(unsigned short, __float2bfloat16(a));
    unsigned hi = (unsigned)__builtin_bit_cast(unsigned short, __float2bfloat16(b));
    return lo | (hi << 16);
}

// ---------------------------------------------------------------------------
// Fold kernel: 72 blocks x 512 threads. Same math as verified rounds 2-6,
// re-indexed for 512 threads (half per-thread work in every matmul stage).
// ---------------------------------------------------------------------------
#define FS 68   // fold matmul LDS row stride (floats); 16B-aligned, 2-way banks

__global__ __launch_bounds__(512) void tt_fold(
    const float* __restrict__ Ag,    // (4,128,64)
    const float* __restrict__ Bg,    // (4,64,64)
    const float* __restrict__ Abg,   // (4,1,64)
    const float* __restrict__ Utg,   // (4,128,64)
    const float* __restrict__ btg,   // (4,1,64)
    const float* __restrict__ Uog,   // (4,64,128)
    const float* __restrict__ bog,   // (4,1,128)
    unsigned short* __restrict__ Wp, // [34][8][512][8] bf16
    float* __restrict__ biasOut)     // [512]
{
    __shared__ __align__(16) float L[23552];   // 92 KB
    const int t = threadIdx.x;
    const int bid = blockIdx.x;

    // d = x @ y (+ add), 64x64, row stride FS. 512 thr: 8 cols/thread.
    auto mm = [&](float* d, const float* x, const float* y, const float* add) {
        const int r = t >> 3, c0 = (t & 7) << 3;
        float acc[8];
#pragma unroll
        for (int j = 0; j < 8; ++j) acc[j] = 0.f;
        for (int k = 0; k < 64; ++k) {
            const float a = x[r * FS + k];
            const float4 y0 = *(const float4*)(y + k * FS + c0);
            const float4 y1 = *(const float4*)(y + k * FS + c0 + 4);
            acc[0] += a * y0.x; acc[1] += a * y0.y;
            acc[2] += a * y0.z; acc[3] += a * y0.w;
            acc[4] += a * y1.x; acc[5] += a * y1.y;
            acc[6] += a * y1.z; acc[7] += a * y1.w;
        }
        if (add) {
#pragma unroll
            for (int j = 0; j < 8; ++j) acc[j] += add[r * FS + c0 + j];
        }
#pragma unroll
        for (int j = 0; j < 8; ++j) d[r * FS + c0 + j] = acc[j];
    };

    float* buf[4];
    buf[0] = L;
    buf[1] = L + 4352;
    buf[2] = L + 8704;
    buf[3] = L + 13056;
    float* const Pbuf = L + 17408;   // 64x64 dense (stride 64)
    float* const UC   = L + 21504;   // 16x128 staging

    if (bid < 68) {
        int a, p, kbase;
        const float* src;
        if (bid < 64) { a = bid >> 4; const int c = bid & 15; p = 15 - c; kbase = c * 128; src = Ag  + a * 8192; }
        else          { a = bid - 64; p = 16; kbase = 2048;               src = Utg + a * 8192; }
        const float* Bmat = Bg + a * 4096;

        for (int i = t; i < 4096; i += 512) {
            const int row = i >> 6, col = i & 63;
            buf[0][row * FS + col] = Bmat[i];
            buf[2][row * FS + col] = (row == col) ? 1.f : 0.f;
        }
        __syncthreads();
        int bcur = 0, rcur = 2;
        int e = p;
        while (e) {
            if (e & 1) { mm(buf[rcur ^ 1], buf[rcur], buf[bcur], nullptr); rcur ^= 1; __syncthreads(); }
            e >>= 1;
            if (e)     { mm(buf[bcur ^ 1], buf[bcur], buf[bcur], nullptr); bcur ^= 1; __syncthreads(); }
        }

        // copy P = B^p to dense stride-64 region
        {
            const int prow = t >> 3, pc0 = (t & 7) << 3;
#pragma unroll
            for (int j = 0; j < 8; ++j)
                Pbuf[prow * 64 + pc0 + j] = buf[rcur][prow * FS + pc0 + j];
        }
        __syncthreads();

        // M1 = src(128x64) @ P, stored stride-65 at L (bufs dead now)
        float* M1 = L;
        {
            const int i = t >> 2, r0 = (t & 3) << 4;
            float acc[16];
#pragma unroll
            for (int j = 0; j < 16; ++j) acc[j] = 0.f;
            for (int q = 0; q < 64; ++q) {
                const float av = src[i * 64 + q];
                const float4* pr = (const float4*)(Pbuf + q * 64 + r0);
#pragma unroll
                for (int jj = 0; jj < 4; ++jj) {
                    float4 v = pr[jj];
                    acc[4 * jj + 0] += av * v.x;
                    acc[4 * jj + 1] += av * v.y;
                    acc[4 * jj + 2] += av * v.z;
                    acc[4 * jj + 3] += av * v.w;
                }
            }
#pragma unroll
            for (int j = 0; j < 16; ++j) M1[i * 65 + r0 + j] = acc[j];
        }
        __syncthreads();

        // W2 = M1(128x64) @ Uo(64x128); Uo staged 16 rows/chunk
        const float* UoA = Uog + a * 8192;
        const int i = t >> 2, h0 = (t & 3) << 5;
        float acc2[32];
#pragma unroll
        for (int j = 0; j < 32; ++j) acc2[j] = 0.f;
        for (int ch = 0; ch < 4; ++ch) {
            __syncthreads();
            for (int idx = t; idx < 2048; idx += 512) UC[idx] = UoA[ch * 2048 + idx];
            __syncthreads();
            for (int rr = 0; rr < 16; ++rr) {
                const float m = M1[i * 65 + ch * 16 + rr];
                const float4* ur = (const float4*)(UC + rr * 128 + h0);
#pragma unroll
                for (int jj = 0; jj < 8; ++jj) {
                    float4 v = ur[jj];
                    acc2[4 * jj + 0] += m * v.x;
                    acc2[4 * jj + 1] += m * v.y;
                    acc2[4 * jj + 2] += m * v.z;
                    acc2[4 * jj + 3] += m * v.w;
                }
            }
        }
        // write fragment-ordered image: [kt][slot][n][widx]
        {
            const int k = kbase + i;
            const int kt = k >> 6, slot = (k >> 3) & 7, widx = k & 7;
#pragma unroll
            for (int j = 0; j < 32; ++j) {
                const int n = a * 128 + h0 + j;
                Wp[((size_t)(kt * 8 + slot) * 512 + n) * 8 + widx] =
                    (unsigned short)f2bfbits(acc2[j]);
            }
        }
    } else {
        // bias: S16 = sum_{p<16} B^p, B16 = B^16
        const int a = bid - 68;
        const float* Bmat = Bg + a * 4096;
        for (int i = t; i < 4096; i += 512) {
            const int row = i >> 6, col = i & 63;
            buf[0][row * FS + col] = Bmat[i];
            buf[2][row * FS + col] = (row == col) ? 1.f : 0.f;
        }
        __syncthreads();
        int bcur = 0, scur = 2;
        for (int rnd = 0; rnd < 4; ++rnd) {
            mm(buf[scur ^ 1], buf[bcur], buf[scur], buf[scur]);
            mm(buf[bcur ^ 1], buf[bcur], buf[bcur], nullptr);
            __syncthreads();
            scur ^= 1; bcur ^= 1;
        }
        float* vv = Pbuf;
        if (t < 64) {
            float acc = 0.f;
            const float* S16 = buf[scur];
            const float* B16 = buf[bcur];
            for (int q = 0; q < 64; ++q)
                acc += Abg[a * 64 + q] * S16[q * FS + t]
                     + btg[a * 64 + q] * B16[q * FS + t];
            vv[t] = acc;
        }
        __syncthreads();
        if (t < 128) {
            float accb = bog[a * 128 + t];
            const float* UoA = Uog + a * 8192;
            for (int r = 0; r < 64; ++r) accb += vv[r] * UoA[r * 128 + t];
            biasOut[a * 128 + t] = accb;
        }
    }
}
#undef FS

// ---------------------------------------------------------------------------
// Main GEMM: 1024 blocks x 256 threads (4 waves), block 64M x 256N,
// wave 64x64, BK=64 (34 K-tiles). A-only LDS (2 x 8KB). B-frags from
// L2-resident Wp with DISTANCE-1 named double-buffer (bFA/bFB); A loads
// distance-2 (va0/va1). No load latency exposed inside an iteration.
// ---------------------------------------------------------------------------
__global__ __launch_bounds__(256, 4) void tt_gemm(
    const float* __restrict__ nh,           // (32768,16,128)
    const float* __restrict__ te,           // (32768,128)
    const unsigned short* __restrict__ Wp,  // [34][8][512][8] bf16
    const float* __restrict__ bias,         // [512]
    float* __restrict__ out)                // (32768,512)
{
    __shared__ __align__(16) char Ab[16384];   // [d][kk][lg][row 0..63][16B]

    const int t = threadIdx.x;
    const int lane = t & 63, wave = t >> 6;
    // chunked XCD map: the two n-halves of one m-tile land on the same XCD.
    const int lt = (blockIdx.x & 7) * 128 + (blockIdx.x >> 3);  // 1024 = 8*128
    const int m0 = (lt >> 1) * 64;
    const int wc = (lt & 1) * 4 + wave;          // n-col group 0..7
    const int lx = lane & 15, lg = lane >> 4;

    // A staging: thread -> row r (0..63), k-chunk c (16 f32)
    const int r = t >> 2, c = t & 3;
    const float* nhp = nh + (size_t)(m0 + r) * 2048 + c * 16;
    const float* tep = te + (size_t)(m0 + r) * 128  + c * 16;
    const int awoff = (c >> 1) * 4096 + (c & 1) * 2048 + r * 16;
    const int aroff = lg * 1024 + lx * 16;       // + d*8192 + kk*4096 + fm*256

    // B frag byte base: + kt*65536 + kk*32768 + fn*256
    const char* const wbase = (const char*)Wp + lg * 8192 + wc * 1024 + lx * 16;

    f32x4 acc[4][4] = {};
    float4 va0[4], va1[4];   // A staging (distance-2)
    uint4  bFA[4][2], bFB[4][2];  // B frags (distance-1 double buffer)

#define LOADA(dst, kt_) do {                                                   \
    const float* _p = ((kt_) < 32) ? (nhp + (kt_) * 64) : (tep + ((kt_) - 32) * 64); \
    _Pragma("unroll")                                                          \
    for (int _j = 0; _j < 4; ++_j) dst[_j] = *(const float4*)(_p + 4 * _j);    \
} while (0)

#define WRITEA(src, d_) do {                                                   \
    uint4 _w0, _w1;                                                            \
    _w0.x = pack2(src[0].x, src[0].y);  _w0.y = pack2(src[0].z, src[0].w);     \
    _w0.z = pack2(src[1].x, src[1].y);  _w0.w = pack2(src[1].z, src[1].w);     \
    _w1.x = pack2(src[2].x, src[2].y);  _w1.y = pack2(src[2].z, src[2].w);     \
    _w1.z = pack2(src[3].x, src[3].y);  _w1.w = pack2(src[3].z, src[3].w);     \
    *(uint4*)(Ab + (d_) * 8192 + awoff)        = _w0;                          \
    *(uint4*)(Ab + (d_) * 8192 + awoff + 1024) = _w1;                          \
} while (0)

#define LOADB(dst, kt_) do {                                                   \
    const char* _q = wbase + (size_t)(kt_) * 65536;                            \
    _Pragma("unroll")                                                          \
    for (int _kk = 0; _kk < 2; ++_kk)                                          \
        _Pragma("unroll")                                                      \
        for (int _fn = 0; _fn < 4; ++_fn)                                      \
            dst[_fn][_kk] = *(const uint4*)(_q + _kk * 32768 + _fn * 256);     \
} while (0)

#define COMPUTE(d_, bsrc) do {                                                 \
    _Pragma("unroll")                                                          \
    for (int _kk = 0; _kk < 2; ++_kk) {                                        \
        bf16x8 _aF[4];                                                         \
        _Pragma("unroll")                                                      \
        for (int _fm = 0; _fm < 4; ++_fm)                                      \
            _aF[_fm] = *(const bf16x8*)(Ab + (d_) * 8192 + _kk * 4096 + aroff + _fm * 256); \
        _Pragma("unroll")                                                      \
        for (int _fm = 0; _fm < 4; ++_fm)                                      \
            _Pragma("unroll")                                                  \
            for (int _fn = 0; _fn < 4; ++_fn)                                  \
                acc[_fm][_fn] = __builtin_amdgcn_mfma_f32_16x16x32_bf16(       \
                    _aF[_fm], __builtin_bit_cast(bf16x8, bsrc[_fn][_kk]),      \
                    acc[_fm][_fn], 0, 0, 0);                                   \
    }                                                                          \
} while (0)

    // prologue: A tile0 -> buf0; A tile1 + B tile0 in flight
    LOADA(va0, 0);
    WRITEA(va0, 0);
    LOADA(va1, 1);
    LOADB(bFA, 0);
    __syncthreads();

#pragma unroll 1
    for (int kt = 0; kt < 34; kt += 2) {
        // ---- even: compute tile kt (buf0, bFA); prefetch B(kt+1), A(kt+2) ----
        LOADB(bFB, kt + 1);
        if (kt + 2 < 34) LOADA(va0, kt + 2);
        COMPUTE(0, bFA);
        WRITEA(va1, 1);                   // va1 loaded a full iteration ago
        __syncthreads();

        // ---- odd: compute tile kt+1 (buf1, bFB); prefetch B(kt+2), A(kt+3) ----
        if (kt + 2 < 34) LOADB(bFA, kt + 2);
        if (kt + 3 < 34) LOADA(va1, kt + 3);
        COMPUTE(1, bFB);
        if (kt + 2 < 34) WRITEA(va0, 0);
        __syncthreads();
    }
#undef LOADA
#undef WRITEA
#undef LOADB
#undef COMPUTE

    // epilogue: C/D layout col = lane&15, row = (lane>>4)*4 + reg  [m89]
    const int orow = m0 + lg * 4;
    const int ocol = wc * 64 + lx;
    float bv[4];
#pragma unroll
    for (int fn = 0; fn < 4; ++fn) bv[fn] = bias[ocol + fn * 16];
#pragma unroll
    for (int fm = 0; fm < 4; ++fm)
#pragma unroll
        for (int fn = 0; fn < 4; ++fn)
#pragma unroll
            for (int j = 0; j < 4; ++j)
                out[(size_t)(orow + fm * 16 + j) * 512 + ocol + fn * 16] =
                    acc[fm][fn][j] + bv[fn];
}

// ---------------------------------------------------------------------------
extern "C" void kernel_launch(void* const* d_in, const int* in_sizes, int n_in,
                              void* d_out, int out_size, void* d_ws, size_t ws_size,
                              hipStream_t stream) {
    const float* nh  = (const float*)d_in[0];
    const float* te  = (const float*)d_in[1];
    const float* Ag  = (const float*)d_in[2];
    const float* Bg  = (const float*)d_in[3];
    const float* Abg = (const float*)d_in[4];
    const float* Utg = (const float*)d_in[5];
    const float* btg = (const float*)d_in[6];
    const float* Uog = (const float*)d_in[7];
    const float* bog = (const float*)d_in[8];

    unsigned short* Wp = (unsigned short*)d_ws;              // 34*8*512*8*2 B
    float* bias = (float*)((char*)d_ws + (size_t)34 * 8 * 512 * 8 * 2);
    float* out = (float*)d_out;

    hipLaunchKernelGGL(tt_fold, dim3(72), dim3(512), 0, stream,
                       Ag, Bg, Abg, Utg, btg, Uog, bog, Wp, bias);
    hipLaunchKernelGGL(tt_gemm, dim3(1024), dim3(256), 0, stream,
                       nh, te, Wp, bias, out);
}

// Round 8
// 211.011 us; speedup vs baseline: 3.9772x; 3.9772x over previous
//
#include <hip/hip_runtime.h>
#include <hip/hip_bf16.h>

// TensorTrainLMN: out[b, a*128+h] = X[b,:] @ W[:, a*128+h] + bias
//   X[b] = [nh[b,0,:128], ..., nh[b,15,:128], te[b,:128]]   (K = 2176)
// tt_fold: folds A@B^(15-c)@U_out (exact f32) into W bf16, PRE-PACKED in MFMA
//   B-fragment order: Wp[kt][slot=k8][n 0..511][8 bf16]. 512 threads/block.
// tt_gemm: A-only-LDS MFMA GEMM (W 2.2MB = L2-resident, B-frags global->VGPR).
//   256 thr / 4 waves, block 64Mx256N, wave 64x64, BK=64. KEY CHANGE vs r6:
//   raw s_barrier + lgkmcnt(0) only (NO vmcnt drain) -> the bFA/bFB and
//   va0/va1 register prefetches genuinely stay in flight across barriers;
//   compiler's counted vmcnt before each register use gives correctness.
//   No min-occupancy launch bound (r7's spill cause).

typedef short bf16x8 __attribute__((ext_vector_type(8)));
typedef float f32x4  __attribute__((ext_vector_type(4)));

__device__ __forceinline__ unsigned f2bfbits(float f) {
    unsigned u = __builtin_bit_cast(unsigned, f);
    return (u + 0x7FFFu + ((u >> 16) & 1u)) >> 16;   // round-to-nearest-even
}
// compiler fuses pairs into v_cvt_pk_bf16_f32 (m240)
__device__ __forceinline__ unsigned pack2(float a, float b) {
    unsigned lo = (unsigned)__builtin_bit_cast(unsigned short, __float2bfloat16(a));
    unsigned hi = (unsigned)__builtin_bit_cast(unsigned short, __float2bfloat16(b));
    return lo | (hi << 16);
}

// publish LDS writes, cross barrier WITHOUT draining vmem prefetches
#define SYNC_NODRAIN() do {                                   \
    asm volatile("s_waitcnt lgkmcnt(0)" ::: "memory");        \
    __builtin_amdgcn_s_barrier();                             \
} while (0)

// ---------------------------------------------------------------------------
// Fold kernel: 72 blocks x 512 threads (verified r7; math verified r2-r7).
// ---------------------------------------------------------------------------
#define FS 68   // fold matmul LDS row stride (floats); 16B-aligned, 2-way banks

__global__ __launch_bounds__(512) void tt_fold(
    const float* __restrict__ Ag,    // (4,128,64)
    const float* __restrict__ Bg,    // (4,64,64)
    const float* __restrict__ Abg,   // (4,1,64)
    const float* __restrict__ Utg,   // (4,128,64)
    const float* __restrict__ btg,   // (4,1,64)
    const float* __restrict__ Uog,   // (4,64,128)
    const float* __restrict__ bog,   // (4,1,128)
    unsigned short* __restrict__ Wp, // [34][8][512][8] bf16
    float* __restrict__ biasOut)     // [512]
{
    __shared__ __align__(16) float L[23552];   // 92 KB
    const int t = threadIdx.x;
    const int bid = blockIdx.x;

    auto mm = [&](float* d, const float* x, const float* y, const float* add) {
        const int r = t >> 3, c0 = (t & 7) << 3;
        float acc[8];
#pragma unroll
        for (int j = 0; j < 8; ++j) acc[j] = 0.f;
        for (int k = 0; k < 64; ++k) {
            const float a = x[r * FS + k];
            const float4 y0 = *(const float4*)(y + k * FS + c0);
            const float4 y1 = *(const float4*)(y + k * FS + c0 + 4);
            acc[0] += a * y0.x; acc[1] += a * y0.y;
            acc[2] += a * y0.z; acc[3] += a * y0.w;
            acc[4] += a * y1.x; acc[5] += a * y1.y;
            acc[6] += a * y1.z; acc[7] += a * y1.w;
        }
        if (add) {
#pragma unroll
            for (int j = 0; j < 8; ++j) acc[j] += add[r * FS + c0 + j];
        }
#pragma unroll
        for (int j = 0; j < 8; ++j) d[r * FS + c0 + j] = acc[j];
    };

    float* buf[4];
    buf[0] = L;
    buf[1] = L + 4352;
    buf[2] = L + 8704;
    buf[3] = L + 13056;
    float* const Pbuf = L + 17408;   // 64x64 dense (stride 64)
    float* const UC   = L + 21504;   // 16x128 staging

    if (bid < 68) {
        int a, p, kbase;
        const float* src;
        if (bid < 64) { a = bid >> 4; const int c = bid & 15; p = 15 - c; kbase = c * 128; src = Ag  + a * 8192; }
        else          { a = bid - 64; p = 16; kbase = 2048;               src = Utg + a * 8192; }
        const float* Bmat = Bg + a * 4096;

        for (int i = t; i < 4096; i += 512) {
            const int row = i >> 6, col = i & 63;
            buf[0][row * FS + col] = Bmat[i];
            buf[2][row * FS + col] = (row == col) ? 1.f : 0.f;
        }
        __syncthreads();
        int bcur = 0, rcur = 2;
        int e = p;
        while (e) {
            if (e & 1) { mm(buf[rcur ^ 1], buf[rcur], buf[bcur], nullptr); rcur ^= 1; __syncthreads(); }
            e >>= 1;
            if (e)     { mm(buf[bcur ^ 1], buf[bcur], buf[bcur], nullptr); bcur ^= 1; __syncthreads(); }
        }

        {
            const int prow = t >> 3, pc0 = (t & 7) << 3;
#pragma unroll
            for (int j = 0; j < 8; ++j)
                Pbuf[prow * 64 + pc0 + j] = buf[rcur][prow * FS + pc0 + j];
        }
        __syncthreads();

        // M1 = src(128x64) @ P, stored stride-65 at L (bufs dead now)
        float* M1 = L;
        {
            const int i = t >> 2, r0 = (t & 3) << 4;
            float acc[16];
#pragma unroll
            for (int j = 0; j < 16; ++j) acc[j] = 0.f;
            for (int q = 0; q < 64; ++q) {
                const float av = src[i * 64 + q];
                const float4* pr = (const float4*)(Pbuf + q * 64 + r0);
#pragma unroll
                for (int jj = 0; jj < 4; ++jj) {
                    float4 v = pr[jj];
                    acc[4 * jj + 0] += av * v.x;
                    acc[4 * jj + 1] += av * v.y;
                    acc[4 * jj + 2] += av * v.z;
                    acc[4 * jj + 3] += av * v.w;
                }
            }
#pragma unroll
            for (int j = 0; j < 16; ++j) M1[i * 65 + r0 + j] = acc[j];
        }
        __syncthreads();

        // W2 = M1(128x64) @ Uo(64x128); Uo staged 16 rows/chunk
        const float* UoA = Uog + a * 8192;
        const int i = t >> 2, h0 = (t & 3) << 5;
        float acc2[32];
#pragma unroll
        for (int j = 0; j < 32; ++j) acc2[j] = 0.f;
        for (int ch = 0; ch < 4; ++ch) {
            __syncthreads();
            for (int idx = t; idx < 2048; idx += 512) UC[idx] = UoA[ch * 2048 + idx];
            __syncthreads();
            for (int rr = 0; rr < 16; ++rr) {
                const float m = M1[i * 65 + ch * 16 + rr];
                const float4* ur = (const float4*)(UC + rr * 128 + h0);
#pragma unroll
                for (int jj = 0; jj < 8; ++jj) {
                    float4 v = ur[jj];
                    acc2[4 * jj + 0] += m * v.x;
                    acc2[4 * jj + 1] += m * v.y;
                    acc2[4 * jj + 2] += m * v.z;
                    acc2[4 * jj + 3] += m * v.w;
                }
            }
        }
        {
            const int k = kbase + i;
            const int kt = k >> 6, slot = (k >> 3) & 7, widx = k & 7;
#pragma unroll
            for (int j = 0; j < 32; ++j) {
                const int n = a * 128 + h0 + j;
                Wp[((size_t)(kt * 8 + slot) * 512 + n) * 8 + widx] =
                    (unsigned short)f2bfbits(acc2[j]);
            }
        }
    } else {
        // bias: S16 = sum_{p<16} B^p, B16 = B^16
        const int a = bid - 68;
        const float* Bmat = Bg + a * 4096;
        for (int i = t; i < 4096; i += 512) {
            const int row = i >> 6, col = i & 63;
            buf[0][row * FS + col] = Bmat[i];
            buf[2][row * FS + col] = (row == col) ? 1.f : 0.f;
        }
        __syncthreads();
        int bcur = 0, scur = 2;
        for (int rnd = 0; rnd < 4; ++rnd) {
            mm(buf[scur ^ 1], buf[bcur], buf[scur], buf[scur]);
            mm(buf[bcur ^ 1], buf[bcur], buf[bcur], nullptr);
            __syncthreads();
            scur ^= 1; bcur ^= 1;
        }
        float* vv = Pbuf;
        if (t < 64) {
            float acc = 0.f;
            const float* S16 = buf[scur];
            const float* B16 = buf[bcur];
            for (int q = 0; q < 64; ++q)
                acc += Abg[a * 64 + q] * S16[q * FS + t]
                     + btg[a * 64 + q] * B16[q * FS + t];
            vv[t] = acc;
        }
        __syncthreads();
        if (t < 128) {
            float accb = bog[a * 128 + t];
            const float* UoA = Uog + a * 8192;
            for (int r = 0; r < 64; ++r) accb += vv[r] * UoA[r * 128 + t];
            biasOut[a * 128 + t] = accb;
        }
    }
}
#undef FS

// ---------------------------------------------------------------------------
// Main GEMM: 1024 blocks x 256 threads (4 waves), block 64M x 256N,
// wave 64x64, BK=64 (34 K-tiles). A-only LDS (2 x 8KB). B-frags distance-1
// named double-buffer (bFA/bFB); A distance-2 (va0/va1). Barriers are raw
// s_barrier + lgkmcnt(0) -> vmem prefetches survive across iterations.
// ---------------------------------------------------------------------------
__global__ __launch_bounds__(256) void tt_gemm(
    const float* __restrict__ nh,           // (32768,16,128)
    const float* __restrict__ te,           // (32768,128)
    const unsigned short* __restrict__ Wp,  // [34][8][512][8] bf16
    const float* __restrict__ bias,         // [512]
    float* __restrict__ out)                // (32768,512)
{
    __shared__ __align__(16) char Ab[16384];   // [d][kk][lg][row 0..63][16B]

    const int t = threadIdx.x;
    const int lane = t & 63, wave = t >> 6;
    // chunked XCD map: the two n-halves of one m-tile land on the same XCD.
    const int lt = (blockIdx.x & 7) * 128 + (blockIdx.x >> 3);  // 1024 = 8*128
    const int m0 = (lt >> 1) * 64;
    const int wc = (lt & 1) * 4 + wave;          // n-col group 0..7
    const int lx = lane & 15, lg = lane >> 4;

    // A staging: thread -> row r (0..63), k-chunk c (16 f32)
    const int r = t >> 2, c = t & 3;
    const float* nhp = nh + (size_t)(m0 + r) * 2048 + c * 16;
    const float* tep = te + (size_t)(m0 + r) * 128  + c * 16;
    const int awoff = (c >> 1) * 4096 + (c & 1) * 2048 + r * 16;
    const int aroff = lg * 1024 + lx * 16;       // + d*8192 + kk*4096 + fm*256

    // B frag byte base: + kt*65536 + kk*32768 + fn*256
    const char* const wbase = (const char*)Wp + lg * 8192 + wc * 1024 + lx * 16;

    f32x4 acc[4][4] = {};
    float4 va0[4], va1[4];        // A staging (distance-2)
    uint4  bFA[4][2], bFB[4][2];  // B frags (distance-1 double buffer)

#define LOADA(dst, kt_) do {                                                   \
    const float* _p = ((kt_) < 32) ? (nhp + (kt_) * 64) : (tep + ((kt_) - 32) * 64); \
    _Pragma("unroll")                                                          \
    for (int _j = 0; _j < 4; ++_j) dst[_j] = *(const float4*)(_p + 4 * _j);    \
} while (0)

#define WRITEA(src, d_) do {                                                   \
    uint4 _w0, _w1;                                                            \
    _w0.x = pack2(src[0].x, src[0].y);  _w0.y = pack2(src[0].z, src[0].w);     \
    _w0.z = pack2(src[1].x, src[1].y);  _w0.w = pack2(src[1].z, src[1].w);     \
    _w1.x = pack2(src[2].x, src[2].y);  _w1.y = pack2(src[2].z, src[2].w);     \
    _w1.z = pack2(src[3].x, src[3].y);  _w1.w = pack2(src[3].z, src[3].w);     \
    *(uint4*)(Ab + (d_) * 8192 + awoff)        = _w0;                          \
    *(uint4*)(Ab + (d_) * 8192 + awoff + 1024) = _w1;                          \
} while (0)

#define LOADB(dst, kt_) do {                                                   \
    const char* _q = wbase + (size_t)(kt_) * 65536;                            \
    _Pragma("unroll")                                                          \
    for (int _kk = 0; _kk < 2; ++_kk)                                          \
        _Pragma("unroll")                                                      \
        for (int _fn = 0; _fn < 4; ++_fn)                                      \
            dst[_fn][_kk] = *(const uint4*)(_q + _kk * 32768 + _fn * 256);     \
} while (0)

#define COMPUTE(d_, bsrc) do {                                                 \
    _Pragma("unroll")                                                          \
    for (int _kk = 0; _kk < 2; ++_kk) {                                        \
        bf16x8 _aF[4];                                                         \
        _Pragma("unroll")                                                      \
        for (int _fm = 0; _fm < 4; ++_fm)                                      \
            _aF[_fm] = *(const bf16x8*)(Ab + (d_) * 8192 + _kk * 4096 + aroff + _fm * 256); \
        _Pragma("unroll")                                                      \
        for (int _fm = 0; _fm < 4; ++_fm)                                      \
            _Pragma("unroll")                                                  \
            for (int _fn = 0; _fn < 4; ++_fn)                                  \
                acc[_fm][_fn] = __builtin_amdgcn_mfma_f32_16x16x32_bf16(       \
                    _aF[_fm], __builtin_bit_cast(bf16x8, bsrc[_fn][_kk]),      \
                    acc[_fm][_fn], 0, 0, 0);                                   \
    }                                                                          \
} while (0)

    // prologue: A tile0 -> buf0; A tile1 + B tile0 in flight
    LOADA(va0, 0);
    WRITEA(va0, 0);
    LOADA(va1, 1);
    LOADB(bFA, 0);
    SYNC_NODRAIN();

#pragma unroll 1
    for (int kt = 0; kt < 34; kt += 2) {
        // ---- even: compute tile kt (buf0, bFA); prefetch B(kt+1), A(kt+2) ----
        LOADB(bFB, kt + 1);
        if (kt + 2 < 34) LOADA(va0, kt + 2);
        COMPUTE(0, bFA);
        WRITEA(va1, 1);                   // va1 loaded a full iteration ago
        SYNC_NODRAIN();

        // ---- odd: compute tile kt+1 (buf1, bFB); prefetch B(kt+2), A(kt+3) ----
        if (kt + 2 < 34) LOADB(bFA, kt + 2);
        if (kt + 3 < 34) LOADA(va1, kt + 3);
        COMPUTE(1, bFB);
        if (kt + 2 < 34) WRITEA(va0, 0);
        SYNC_NODRAIN();
    }
#undef LOADA
#undef WRITEA
#undef LOADB
#undef COMPUTE

    // epilogue: C/D layout col = lane&15, row = (lane>>4)*4 + reg  [m89]
    const int orow = m0 + lg * 4;
    const int ocol = wc * 64 + lx;
    float bv[4];
#pragma unroll
    for (int fn = 0; fn < 4; ++fn) bv[fn] = bias[ocol + fn * 16];
#pragma unroll
    for (int fm = 0; fm < 4; ++fm)
#pragma unroll
        for (int fn = 0; fn < 4; ++fn)
#pragma unroll
            for (int j = 0; j < 4; ++j)
                out[(size_t)(orow + fm * 16 + j) * 512 + ocol + fn * 16] =
                    acc[fm][fn][j] + bv[fn];
}

// ---------------------------------------------------------------------------
extern "C" void kernel_launch(void* const* d_in, const int* in_sizes, int n_in,
                              void* d_out, int out_size, void* d_ws, size_t ws_size,
                              hipStream_t stream) {
    const float* nh  = (const float*)d_in[0];
    const float* te  = (const float*)d_in[1];
    const float* Ag  = (const float*)d_in[2];
    const float* Bg  = (const float*)d_in[3];
    const float* Abg = (const float*)d_in[4];
    const float* Utg = (const float*)d_in[5];
    const float* btg = (const float*)d_in[6];
    const float* Uog = (const float*)d_in[7];
    const float* bog = (const float*)d_in[8];

    unsigned short* Wp = (unsigned short*)d_ws;              // 34*8*512*8*2 B
    float* bias = (float*)((char*)d_ws + (size_t)34 * 8 * 512 * 8 * 2);
    float* out = (float*)d_out;

    hipLaunchKernelGGL(tt_fold, dim3(72), dim3(512), 0, stream,
                       Ag, Bg, Abg, Utg, btg, Uog, bog, Wp, bias);
    hipLaunchKernelGGL(tt_gemm, dim3(1024), dim3(256), 0, stream,
                       nh, te, Wp, bias, out);
}